// Round 5
// baseline (7800.388 us; speedup 1.0000x reference)
//
#include <hip/hip_runtime.h>

// Problem constants
#define BB    128   // batch
#define LL    2048  // seq len
#define FF    128   // input features
#define HH    256   // hidden
#define OO    128   // output
#define NTICK 5
#define GC    16    // chains per consumer group
#define NCG   8     // consumer groups (blocks 0..7)
#define CH    4     // timesteps per ring chunk
#define DRING 128   // ring depth (timesteps)
#define NPS   8     // producer col-slices (96 cols each)
#define NPL   16    // producer chunk-lanes
#define MAXT  (LL + NTICK)
#define MAXCH ((MAXT + CH - 1) / CH)
#define RDY8  0x0101010101010101ULL

typedef __attribute__((ext_vector_type(8))) _Float16 half8;
typedef __attribute__((ext_vector_type(4))) float f32x4;

union U64H4 { unsigned long long u; _Float16 h[4]; };

__device__ __forceinline__ float fast_rcp(float x) { return __builtin_amdgcn_rcpf(x); }

// Relaxed system-scope ops (sc0 sc1): bypass L1/L2, coherent at MALL.
// RELAXED => no buffer_inv/buffer_wbl2 cache maintenance emitted.
__device__ __forceinline__ unsigned long long sysload_u64(const unsigned long long* p) {
  return __hip_atomic_load(p, __ATOMIC_RELAXED, __HIP_MEMORY_SCOPE_SYSTEM);
}
__device__ __forceinline__ void sysstore_u64(unsigned long long* p, unsigned long long v) {
  __hip_atomic_store(p, v, __ATOMIC_RELAXED, __HIP_MEMORY_SCOPE_SYSTEM);
}
__device__ __forceinline__ int sysload_i32(const int* p) {
  return __hip_atomic_load(p, __ATOMIC_RELAXED, __HIP_MEMORY_SCOPE_SYSTEM);
}
__device__ __forceinline__ void sysstore_i32(int* p, int v) {
  __hip_atomic_store(p, v, __ATOMIC_RELAXED, __HIP_MEMORY_SCOPE_SYSTEM);
}
__device__ __forceinline__ void sysstore_u8(unsigned char* p, unsigned char v) {
  __hip_atomic_store(p, v, __ATOMIC_RELAXED, __HIP_MEMORY_SCOPE_SYSTEM);
}

// Blocks 0..7: consumers. One chain-group (16 chains) per block, 8 waves.
// Wave wv owns a MATCHED gate triple of columns: for each gate g in {ci,ig,og},
// cols [g*256 + wv*32, g*256 + wv*32 + 32). After D = R^T h^T MFMA (weight
// fragment in the A slot — R4-verified layout), lane (nl, quad) reg r of
// acc[g*2+tt] holds pre[chain=nl][g*256 + wv*32 + tt*16 + quad*4 + r]:
// the ci/ig/og values for one (chain, dim) all live in the SAME lane, so the
// whole gate update runs in-register (c-state in regs, no pre_s/c_s LDS).
// Per step the only LDS traffic is the h broadcast (parity double buffer),
// and the only barrier is one raw s_barrier with lgkmcnt-only drain, so
// system-scope ring loads stay in flight across steps.
//
// Blocks 8..135: producers (as R4): pre_x = bias + tick*[len<=t<len+5]
//   + [t<len]*x_t@W into a 128-step ring, per-chunk ready bytes.
extern "C" __global__ __launch_bounds__(512, 1)
void lstm_all(const float* __restrict__ x, const int* __restrict__ lens,
              const float* __restrict__ W, const float* __restrict__ R,
              const float* __restrict__ bvec, const float* __restrict__ btk,
              unsigned long long* ring, unsigned char* readyb,
              int* prog, float* __restrict__ h_final)
{
  const int tid  = threadIdx.x;
  const int lane = tid & 63;
  const int wv   = tid >> 6;
  const int quad = lane >> 4;
  const int nl   = lane & 15;
  const int bx   = blockIdx.x;

  __shared__ int lens_s[BB];
  if (tid < BB) lens_s[tid] = lens[tid];
  __syncthreads();

  if (bx < NCG) {
    // ======================= CONSUMER =======================
    const int cg = bx, cbase = cg * GC;
    // h parity buffers; row stride 264 halves (132 dw == 4 mod 32) breaks
    // the all-rows-same-bank pattern for the strided writes.
    __shared__ _Float16 h_s[2][GC][264];

    int mxl = 0;
    #pragma unroll
    for (int i = 0; i < GC; i++) mxl = max(mxl, lens_s[cbase + i]);
    const int Tg   = mxl + NTICK;
    const int lenn = lens_s[cbase + nl];

    // R fragments, register-stationary (AGPR-eligible: MFMA A operand).
    // tile = g*2+tt covers cols g*256 + wv*32 + tt*16 + [0,16).
    half8 rfr[6][8];
    #pragma unroll
    for (int tile = 0; tile < 6; tile++) {
      const int col = (tile >> 1) * 256 + wv * 32 + (tile & 1) * 16 + nl;
      #pragma unroll
      for (int kc = 0; kc < 8; kc++) {
        const int k0 = kc * 32 + quad * 8;
        half8 v;
        #pragma unroll
        for (int j = 0; j < 8; j++) v[j] = (_Float16)R[(k0 + j) * (3 * HH) + col];
        rfr[tile][kc] = v;
      }
    }

    float cst[8], hreg[8];
    #pragma unroll
    for (int i = 0; i < 8; i++) { cst[i] = 0.f; hreg[i] = 0.f; }

    const int o0 = wv * 32 + quad * 4;   // dim offset within a gate block

    const unsigned long long* rb = (const unsigned long long*)readyb;
    while (sysload_u64(rb) != RDY8) {}
    asm volatile("" ::: "memory");
    unsigned long long xw[6];
    {
      const unsigned long long* rp = ring + ((((long)cbase + nl) * 768) >> 2);
      xw[0] = sysload_u64(rp + ((o0      ) >> 2));
      xw[1] = sysload_u64(rp + ((o0 +  16) >> 2));
      xw[2] = sysload_u64(rp + ((o0 + 256) >> 2));
      xw[3] = sysload_u64(rp + ((o0 + 272) >> 2));
      xw[4] = sysload_u64(rp + ((o0 + 512) >> 2));
      xw[5] = sysload_u64(rp + ((o0 + 528) >> 2));
    }
    unsigned long long rvn = sysload_u64(rb + 1);
    int cur_chunk = 0;
    __syncthreads();

    for (int t = 0; t < Tg; ++t) {
      f32x4 acc[6];
      #pragma unroll
      for (int i = 0; i < 6; i++) acc[i] = (f32x4){0.f, 0.f, 0.f, 0.f};

      // ---- recurrent MFMA: pre_h = h(t-1) @ R (reads parity (t-1)&1)
      if (t > 0) {
        const _Float16* hb = &h_s[(t - 1) & 1][nl][quad * 8];
        #pragma unroll
        for (int kc = 0; kc < 8; kc++) {
          const half8 a = *(const half8*)(hb + kc * 32);
          #pragma unroll
          for (int tile = 0; tile < 6; tile++)
            acc[tile] = __builtin_amdgcn_mfma_f32_16x16x32_f16(rfr[tile][kc], a, acc[tile], 0, 0, 0);
        }
      }

      // ---- gates, fully in-lane (no LDS round trip)
      if (t < lenn + NTICK) {
        #pragma unroll
        for (int tt = 0; tt < 2; tt++) {
          U64H4 xc, xi, xo2;
          xc.u = xw[tt]; xi.u = xw[2 + tt]; xo2.u = xw[4 + tt];
          #pragma unroll
          for (int r = 0; r < 4; r++) {
            const float pc = acc[tt][r]     + (float)xc.h[r];
            const float pi = acc[2 + tt][r] + (float)xi.h[r];
            const float po = acc[4 + tt][r] + (float)xo2.h[r];
            // tanh(pc)*sigmoid(pi) = (e^{2pc}-1)/((e^{2pc}+1)(1+e^{-pi}))
            const float ea = __expf(2.f * __builtin_fminf(pc, 15.f));
            const float eb = __expf(-pi);
            const float cn = cst[tt * 4 + r] + (ea - 1.f) * fast_rcp((ea + 1.f) * (1.f + eb));
            const float ec = __expf(2.f * __builtin_fminf(cn, 15.f));
            const float ed = __expf(-po);
            hreg[tt * 4 + r] = (ec - 1.f) * fast_rcp((ec + 1.f) * (1.f + ed));
            cst[tt * 4 + r] = cn;
          }
        }
        if (t == lenn + NTICK - 1) {   // final h for this chain, written once
          float* hf = h_final + (cbase + nl) * HH + wv * 32 + quad * 4;
          *(float4*)hf        = make_float4(hreg[0], hreg[1], hreg[2], hreg[3]);
          *(float4*)(hf + 16) = make_float4(hreg[4], hreg[5], hreg[6], hreg[7]);
        }
      }

      // ---- publish h slice to parity buffer (always: frozen lanes republish)
      {
        U64H4 p0, p1;
        #pragma unroll
        for (int r = 0; r < 4; r++) {
          p0.h[r] = (_Float16)hreg[r];
          p1.h[r] = (_Float16)hreg[4 + r];
        }
        _Float16* hw = &h_s[t & 1][nl][o0];
        *(unsigned long long*)hw        = p0.u;
        *(unsigned long long*)(hw + 16) = p1.u;
      }

      // ---- prefetch xw(t+1); loads stay in flight across the raw barrier
      if (t + 1 < Tg) {
        const int nc = (t + 1) >> 2;
        if (nc != cur_chunk) {
          while (rvn != RDY8) rvn = sysload_u64(rb + nc);
          cur_chunk = nc;
          rvn = (nc + 1 < MAXCH) ? sysload_u64(rb + nc + 1) : RDY8;
          asm volatile("" ::: "memory");
        }
        const int slot = (t + 1) & (DRING - 1);
        const unsigned long long* rp = ring + ((((long)slot * BB + cbase + nl) * 768) >> 2);
        xw[0] = sysload_u64(rp + ((o0      ) >> 2));
        xw[1] = sysload_u64(rp + ((o0 +  16) >> 2));
        xw[2] = sysload_u64(rp + ((o0 + 256) >> 2));
        xw[3] = sysload_u64(rp + ((o0 + 272) >> 2));
        xw[4] = sysload_u64(rp + ((o0 + 512) >> 2));
        xw[5] = sysload_u64(rp + ((o0 + 528) >> 2));
      }
      if (tid == 0) sysstore_i32(prog + cg, t);

      // raw barrier: drain LDS only (h_s RAW/WAR across waves); vmem stays
      // in flight — this is the whole point vs __syncthreads' vmcnt(0).
      asm volatile("s_waitcnt lgkmcnt(0)" ::: "memory");
      __builtin_amdgcn_s_barrier();
    }
    if (tid == 0) sysstore_i32(prog + cg, 1 << 20);

  } else {
    // ======================= PRODUCER =======================
    const int pid = bx - NCG;       // 0..127
    const int s   = pid & 7;        // col slice (96 cols)
    const int pl  = pid >> 3;       // chunk lane 0..15

    int mxall = 0;
    #pragma unroll 8
    for (int i = 0; i < BB; i++) mxall = max(mxall, lens_s[i]);
    const int Tall = mxall + NTICK;
    const int nch  = (Tall + CH - 1) / CH;

    half8 wfr[4];
    float bias4[4], tick4[4];
    int col0w = 0;
    if (wv < 6) {
      col0w = s * 96 + wv * 16;
      #pragma unroll
      for (int kc = 0; kc < 4; kc++) {
        const int k0 = kc * 32 + quad * 8;
        half8 v;
        #pragma unroll
        for (int j = 0; j < 8; j++) v[j] = (_Float16)W[(k0 + j) * (3 * HH) + col0w + nl];
        wfr[kc] = v;
      }
      *(float4*)bias4 = *(const float4*)(bvec + col0w + quad * 4);
      *(float4*)tick4 = *(const float4*)(btk  + col0w + quad * 4);
    }

    for (int c = pl; c < nch; c += NPL) {
      if (c * CH >= DRING) {           // flow control: don't overwrite unread slots
        if (tid == 0) {
          const int need = c * CH + CH - DRING;
          for (;;) {
            int mn = 0x7fffffff;
            #pragma unroll
            for (int g = 0; g < NCG; g++) mn = min(mn, sysload_i32(prog + g));
            if (mn >= need) break;
          }
        }
        __syncthreads();
      }
      if (wv < 6) {
        for (int tt = 0; tt < CH; tt++) {
          const int t = c * CH + tt;
          const int slot = t & (DRING - 1);
          #pragma unroll 2
          for (int bt = 0; bt < 8; bt++) {
            const int b = bt * 16 + nl;
            const int lenb = lens_s[b];
            f32x4 acc = {0.f, 0.f, 0.f, 0.f};
            if (t < LL) {
              const float* xp = x + ((long)b * LL + t) * FF + quad * 8;
              #pragma unroll
              for (int kc = 0; kc < 4; kc++) {
                const float4 u0 = *(const float4*)(xp + kc * 32);
                const float4 u1 = *(const float4*)(xp + kc * 32 + 4);
                half8 a;
                a[0] = (_Float16)u0.x; a[1] = (_Float16)u0.y;
                a[2] = (_Float16)u0.z; a[3] = (_Float16)u0.w;
                a[4] = (_Float16)u1.x; a[5] = (_Float16)u1.y;
                a[6] = (_Float16)u1.z; a[7] = (_Float16)u1.w;
                // W-frag in A slot, x-frag in B slot: D = W^T x^T =>
                // lane nl reg r = pre_x[batch=bt*16+nl][col0w+quad*4+r]
                acc = __builtin_amdgcn_mfma_f32_16x16x32_f16(wfr[kc], a, acc, 0, 0, 0);
              }
            }
            U64H4 pk;
            const bool in_x  = (t < lenb);
            const bool in_tk = (t >= lenb) && (t < lenb + NTICK);
            #pragma unroll
            for (int r = 0; r < 4; r++) {
              float v = bias4[r];
              if (in_x)  v += acc[r];
              if (in_tk) v += tick4[r];
              pk.h[r] = (_Float16)v;
            }
            sysstore_u64(ring + ((((long)slot * BB + b) * 768 + col0w + quad * 4) >> 2), pk.u);
          }
        }
      }
      __syncthreads();   // per-wave s_waitcnt vmcnt(0) before barrier => stores drained
      if (tid == 0) sysstore_u8(readyb + c * 8 + s, (unsigned char)1);
    }
  }
}

// out1 = h @ Wp^T + bp   (128x256)
extern "C" __global__ void proj_hp(const float* __restrict__ h,
                                   const float* __restrict__ Wp,
                                   const float* __restrict__ bp,
                                   float* __restrict__ hp)
{
  const int bb = blockIdx.x;
  const int j  = threadIdx.x;  // 256
  const float4* hv = (const float4*)(h + bb * HH);
  const float4* wr = (const float4*)(Wp + j * HH);
  float s = 0.f;
  for (int k = 0; k < HH / 4; k++) {
    const float4 a = hv[k], w = wr[k];
    s += a.x * w.x + a.y * w.y + a.z * w.z + a.w * w.w;
  }
  hp[bb * HH + j] = s + bp[j];
}

// out = hp @ Wo^T + bo   (128x128)
extern "C" __global__ void proj_out(const float* __restrict__ hp,
                                    const float* __restrict__ Wo,
                                    const float* __restrict__ bo,
                                    float* __restrict__ out)
{
  const int bb = blockIdx.x;
  const int o  = threadIdx.x;  // 128
  const float4* hv = (const float4*)(hp + bb * HH);
  const float4* wr = (const float4*)(Wo + o * HH);
  float s = 0.f;
  for (int k = 0; k < HH / 4; k++) {
    const float4 a = hv[k], w = wr[k];
    s += a.x * w.x + a.y * w.y + a.z * w.z + a.w * w.w;
  }
  out[bb * OO + o] = s + bo[o];
}

extern "C" void kernel_launch(void* const* d_in, const int* in_sizes, int n_in,
                              void* d_out, int out_size, void* d_ws, size_t ws_size,
                              hipStream_t stream)
{
  const float* x    = (const float*)d_in[0];
  const int*   ln   = (const int*)  d_in[1];
  const float* W    = (const float*)d_in[2];
  const float* R    = (const float*)d_in[3];
  const float* bvec = (const float*)d_in[4];
  const float* btk  = (const float*)d_in[5];
  const float* Wp   = (const float*)d_in[6];
  const float* bp   = (const float*)d_in[7];
  const float* Wo   = (const float*)d_in[8];
  const float* bo   = (const float*)d_in[9];
  float* out = (float*)d_out;

  // Workspace layout. No init pass needed:
  //   prog[] poisoned 0xAA..: negative => producers wait until consumers publish.
  //   readyb[] poisoned 0xAA != 1 => consumers wait until producers publish.
  char* ws = (char*)d_ws;
  int*                prog    = (int*)ws;                       // 32 B
  unsigned char*      readyb  = (unsigned char*)(ws + 64);      // MAXCH*8 = 4112 B
  float*              h_final = (float*)(ws + 8192);            // 128 KB
  float*              hp      = (float*)(ws + 8192 + 131072);   // 128 KB
  unsigned long long* ring    = (unsigned long long*)(ws + (1 << 20));  // 25.2 MB

  hipLaunchKernelGGL(lstm_all, dim3(NCG + NPS * NPL), dim3(512), 0, stream,
                     x, ln, W, R, bvec, btk, ring, readyb, prog, h_final);
  hipLaunchKernelGGL(proj_hp,  dim3(BB), dim3(HH), 0, stream, h_final, Wp, bp, hp);
  hipLaunchKernelGGL(proj_out, dim3(BB), dim3(OO), 0, stream, hp, Wo, bo, out);
}